// Round 5
// baseline (155.538 us; speedup 1.0000x reference)
//
#include <hip/hip_runtime.h>

// Batched Thomas solve, B=2048 rows, N=8192, fp32. One block per row.
// TB=1024 x CH=8. R5 vs R4: issue-bound (R4: VALUBusy 66%, dur flat across
// configs) => delete instructions, not rearrange:
//  - forward scan split: cp as 4-param Moebius [[0,c],[-a,b]] (8-FLOP compose,
//    4 shuffles/round) + dp as 2-param affine (3-FLOP compose, 2 shuffles/round)
//    replacing the 7-param 3x3 map scan (23-FLOP compose, 7 shuffles/round).
//  - a_i, b_i, c_i, rd_i stashed in registers (R4 had ~30 spare under the
//    64-VGPR/8-wave budget); replays cost 2-7 FLOP/elem instead of 10-14.
// Numerics: Moebius part is a sub-block of the validated 3x3 scan; per-chunk
// v-normalization retained; dp/bwd scans are strong contractions (|G|<=1e-8).

#define NN 8192
#define TB 1024
#define CH 8           // NN / TB
#define NWAVE (TB/64)  // 16

__device__ __forceinline__ float frcp(float x) { return __builtin_amdgcn_rcpf(x); }

__global__ __launch_bounds__(TB, 8)
void thomas_kernel(const float* __restrict__ alpha,
                   const float* __restrict__ fvec,
                   float* __restrict__ out)
{
    __shared__ float wq[NWAVE][4];  // fwd Moebius wave totals (p,q,u,v)
    __shared__ float wd[NWAVE][2];  // dp affine wave totals (G,H)
    __shared__ float wb[NWAVE][2];  // bwd affine wave totals (A,B)

    const int t    = threadIdx.x;
    const int lane = t & 63;
    const int wid  = t >> 6;
    const int row  = blockIdx.x;
    const float* __restrict__ arow = alpha + (size_t)row * NN;
    const int base = t * CH;

    // ---- load alpha chunk + halo and f; precompute a,b,c coefficients ----
    float ai[CH], bi[CH], ci[CH], vf[CH];
    {
        float va[CH];
        const float4* a4 = reinterpret_cast<const float4*>(arow + base);
        const float4* f4 = reinterpret_cast<const float4*>(fvec + base);
        #pragma unroll
        for (int k = 0; k < CH / 4; ++k) {
            float4 x = a4[k];
            va[4*k+0]=x.x; va[4*k+1]=x.y; va[4*k+2]=x.z; va[4*k+3]=x.w;
            float4 y = f4[k];
            vf[4*k+0]=y.x; vf[4*k+1]=y.y; vf[4*k+2]=y.z; vf[4*k+3]=y.w;
        }
        const float aL = (t > 0)      ? arow[base - 1]  : 0.0f;  // => a_0 = 0
        const float aR = (t < TB - 1) ? arow[base + CH] : 0.0f;  // => c_{N-1} = 0
        #pragma unroll
        for (int k = 0; k < CH; ++k) {
            const float am1 = (k == 0)      ? aL : va[k-1];
            const float ap1 = (k == CH - 1) ? aR : va[k+1];
            ai[k] = am1 * am1;
            bi[k] = 1.0f + va[k]*va[k]*va[k];
            ci[k] = ap1 * (ap1 + 2.0f);
        }
    }

    // ---- Phase A: compose chunk Moebius map for cp; normalize v -> 1 ----
    // cp_i = c_i / (b_i - a_i cp_{i-1})  <=>  M_i = [[0, c],[-a, b]]
    float p = 1.f, q = 0.f, u = 0.f, v = 1.f;
    #pragma unroll
    for (int k = 0; k < CH; ++k) {
        const float np = ci[k]*u;
        const float nq = ci[k]*v;
        const float nu = bi[k]*u - ai[k]*p;
        const float nv = bi[k]*v - ai[k]*q;
        p = np; q = nq; u = nu; v = nv;
    }
    { const float inv = frcp(v); p*=inv; q*=inv; u*=inv; v = 1.0f; }

    // ---- wave-inclusive Moebius scan (mine o earlier) ----
    #pragma unroll
    for (int off = 1; off < 64; off <<= 1) {
        const float p1 = __shfl_up(p, off);
        const float q1 = __shfl_up(q, off);
        const float u1 = __shfl_up(u, off);
        const float v1 = __shfl_up(v, off);
        if (lane >= off) {
            const float np = p*p1 + q*u1;
            const float nq = p*q1 + q*v1;
            const float nu = u*p1 + v*u1;
            const float nv = u*q1 + v*v1;
            p = np; q = nq; u = nu; v = nv;
        }
    }
    if (lane == 63) { wq[wid][0]=p; wq[wid][1]=q; wq[wid][2]=u; wq[wid][3]=v; }
    __syncthreads();

    // exclusive-within-wave
    float ep=__shfl_up(p,1), eq=__shfl_up(q,1), eu=__shfl_up(u,1), ev=__shfl_up(v,1);
    if (lane == 0) { ep=1.f; eq=0.f; eu=0.f; ev=1.f; }

    // serial prefix over earlier waves: P = T_{wid-1} o ... o T_0
    float Pp=1.f, Pq=0.f, Pu=0.f, Pv=1.f;
    for (int w = 0; w < wid; ++w) {
        const float p1=wq[w][0], q1=wq[w][1], u1=wq[w][2], v1=wq[w][3];
        const float np = p1*Pp + q1*Pu;
        const float nq = p1*Pq + q1*Pv;
        const float nu = u1*Pp + v1*Pu;
        const float nv = u1*Pq + v1*Pv;
        Pp=np; Pq=nq; Pu=nu; Pv=nv;
    }
    // incoming cp = ex applied to (P applied to 0)
    float cp;
    {
        const float cpP = Pq * frcp(Pv);
        cp = (ep*cpP + eq) * frcp(eu*cpP + ev);
    }

    // ---- Phase C1: cp replay; build dp affine chunk map (G,H) ----
    float cpv[CH], rdv[CH];
    float G = 1.f, H = 0.f;
    #pragma unroll
    for (int k = 0; k < CH; ++k) {
        const float rd = frcp(bi[k] - ai[k]*cp);
        cp = ci[k] * rd;
        cpv[k] = cp; rdv[k] = rd;
        H = (vf[k] - ai[k]*H) * rd;
        G = -(ai[k]*rd) * G;
    }

    // ---- dp affine wave scan (mine o earlier): H = G*H1 + H; G = G*G1 ----
    #pragma unroll
    for (int off = 1; off < 64; off <<= 1) {
        const float G1 = __shfl_up(G, off);
        const float H1 = __shfl_up(H, off);
        if (lane >= off) { H = G*H1 + H; G = G*G1; }
    }
    if (lane == 63) { wd[wid][0] = G; wd[wid][1] = H; }
    __syncthreads();

    float eG = __shfl_up(G, 1), eH = __shfl_up(H, 1);
    if (lane == 0) { eG = 1.f; eH = 0.f; }
    float Pg = 1.f, Ph = 0.f;
    for (int w = 0; w < wid; ++w) {
        const float Gw = wd[w][0], Hw = wd[w][1];
        Ph = Gw*Ph + Hw;   // P = T_w o P
        Pg = Gw*Pg;
    }
    float dp = eG*Ph + eH;   // incoming dp for this chunk

    // ---- Phase C2: dp replay; build backward affine chunk map (A,B) ----
    float dpv[CH];
    #pragma unroll
    for (int k = 0; k < CH; ++k) {
        dp = (vf[k] - ai[k]*dp) * rdv[k];
        dpv[k] = dp;
    }
    float A = 1.f, Bb = 0.f;
    #pragma unroll
    for (int k = CH - 1; k >= 0; --k) {
        Bb = dpv[k] - cpv[k]*Bb;
        A  = -cpv[k]*A;
    }

    // ---- backward wave suffix scan: comp(mine, later) ----
    #pragma unroll
    for (int off = 1; off < 64; off <<= 1) {
        const float A1 = __shfl_down(A, off);
        const float B1 = __shfl_down(Bb, off);
        if (lane < 64 - off) { Bb = A*B1 + Bb; A = A*A1; }
    }
    if (lane == 0) { wb[wid][0] = A; wb[wid][1] = Bb; }
    __syncthreads();

    float eA = __shfl_down(A, 1), eB = __shfl_down(Bb, 1);
    if (lane == 63) { eA = 1.f; eB = 0.f; }
    float SA = 1.f, SB = 0.f;
    for (int w = NWAVE - 1; w > wid; --w) {
        const float Aw = wb[w][0], Bw = wb[w][1];
        SB = Aw*SB + Bw;
        SA = Aw*SA;
    }
    const float u_in = eA*SB + eB;

    // ---- final back-substitution + float4 stores ----
    float uv[CH];
    float un = u_in;
    #pragma unroll
    for (int k = CH - 1; k >= 0; --k) {
        un = dpv[k] - cpv[k]*un;
        uv[k] = un;
    }
    float4* o4 = reinterpret_cast<float4*>(out + (size_t)row * NN + base);
    #pragma unroll
    for (int k = 0; k < CH / 4; ++k) {
        o4[k] = make_float4(uv[4*k+0], uv[4*k+1], uv[4*k+2], uv[4*k+3]);
    }
}

extern "C" void kernel_launch(void* const* d_in, const int* in_sizes, int n_in,
                              void* d_out, int out_size, void* d_ws, size_t ws_size,
                              hipStream_t stream) {
    const float* alpha = (const float*)d_in[0];
    const float* fvec  = (const float*)d_in[1];
    float* out = (float*)d_out;
    const int nrows = out_size / NN;   // 2048
    thomas_kernel<<<nrows, TB, 0, stream>>>(alpha, fvec, out);
}

// Round 6
// 149.694 us; speedup vs baseline: 1.0390x; 1.0390x over previous
//
#include <hip/hip_runtime.h>

// Batched Thomas solve, B=2048 rows, N=8192, fp32. One block per row.
// TB=1024 x CH=8. R6 = R5's slim algebra (Moebius cp-scan + affine dp-scan)
// in R4's proven 32-float register footprint (va, vf, cpv, dpv only).
// R5 FAILED: 56-float stash -> scratch spills (WRITE_SIZE 64->144 MiB).
// Fix: during cp-replay, overwrite va[k-1] <- gk = a*rd (am1's last read is
// earlier in the same iteration) and vf[k] <- hk = f*rd, so the dp replay is
// 1 FMA/elem with zero extra arrays. Budget: 32 floats + ~20 working <= 64
// regs at 8 waves/EU.

#define NN 8192
#define TB 1024
#define CH 8           // NN / TB
#define NWAVE (TB/64)  // 16

__device__ __forceinline__ float frcp(float x) { return __builtin_amdgcn_rcpf(x); }

__global__ __launch_bounds__(TB, 8)
void thomas_kernel(const float* __restrict__ alpha,
                   const float* __restrict__ fvec,
                   float* __restrict__ out)
{
    __shared__ float wq[NWAVE][4];  // fwd Moebius wave totals (p,q,u,v)
    __shared__ float wd[NWAVE][2];  // dp affine wave totals (G,H)
    __shared__ float wb[NWAVE][2];  // bwd affine wave totals (A,B)

    const int t    = threadIdx.x;
    const int lane = t & 63;
    const int wid  = t >> 6;
    const int row  = blockIdx.x;
    const float* __restrict__ arow = alpha + (size_t)row * NN;
    const int base = t * CH;

    // ---- load alpha chunk + halo, f chunk into registers ----
    float va[CH], vf[CH];
    {
        const float4* a4 = reinterpret_cast<const float4*>(arow + base);
        const float4* f4 = reinterpret_cast<const float4*>(fvec + base);
        #pragma unroll
        for (int k = 0; k < CH / 4; ++k) {
            float4 x = a4[k];
            va[4*k+0]=x.x; va[4*k+1]=x.y; va[4*k+2]=x.z; va[4*k+3]=x.w;
            float4 y = f4[k];
            vf[4*k+0]=y.x; vf[4*k+1]=y.y; vf[4*k+2]=y.z; vf[4*k+3]=y.w;
        }
    }
    const float aL = (t > 0)      ? arow[base - 1]  : 0.0f;  // => a_0 = 0
    const float aR = (t < TB - 1) ? arow[base + CH] : 0.0f;  // => c_{N-1} = 0

    // ---- Phase A: compose chunk Moebius map for cp; normalize v -> 1 ----
    // cp_i = c_i/(b_i - a_i cp_{i-1})  <=>  M_i = [[0,c],[-a,b]], coeffs from va.
    float p, q, u, v;
    {
        // k = 0 from identity
        const float ai0 = aL * aL;
        const float bi0 = 1.0f + va[0]*va[0]*va[0];
        const float ci0 = va[1] * (va[1] + 2.0f);
        p = 0.0f; q = ci0; u = -ai0; v = bi0;
    }
    #pragma unroll
    for (int k = 1; k < CH; ++k) {
        const float am1 = va[k-1];
        const float ap1 = (k == CH - 1) ? aR : va[k+1];
        const float ai = am1 * am1;
        const float bi = 1.0f + va[k]*va[k]*va[k];
        const float ci = ap1 * (ap1 + 2.0f);
        const float np = ci*u,        nq = ci*v;
        const float nu = bi*u - ai*p, nv = bi*v - ai*q;
        p = np; q = nq; u = nu; v = nv;
    }
    { const float inv = frcp(v); p*=inv; q*=inv; u*=inv; v = 1.0f; }

    // ---- wave-inclusive Moebius scan (mine o earlier) ----
    #pragma unroll
    for (int off = 1; off < 64; off <<= 1) {
        const float p1 = __shfl_up(p, off);
        const float q1 = __shfl_up(q, off);
        const float u1 = __shfl_up(u, off);
        const float v1 = __shfl_up(v, off);
        if (lane >= off) {
            const float np = p*p1 + q*u1;
            const float nq = p*q1 + q*v1;
            const float nu = u*p1 + v*u1;
            const float nv = u*q1 + v*v1;
            p = np; q = nq; u = nu; v = nv;
        }
    }
    if (lane == 63) { wq[wid][0]=p; wq[wid][1]=q; wq[wid][2]=u; wq[wid][3]=v; }
    __syncthreads();

    // exclusive-within-wave
    float ep=__shfl_up(p,1), eq=__shfl_up(q,1), eu=__shfl_up(u,1), ev=__shfl_up(v,1);
    if (lane == 0) { ep=1.f; eq=0.f; eu=0.f; ev=1.f; }

    // serial prefix over earlier waves: P = T_{wid-1} o ... o T_0
    float Pp=1.f, Pq=0.f, Pu=0.f, Pv=1.f;
    for (int w = 0; w < wid; ++w) {
        const float p1=wq[w][0], q1=wq[w][1], u1=wq[w][2], v1=wq[w][3];
        const float np = p1*Pp + q1*Pu;
        const float nq = p1*Pq + q1*Pv;
        const float nu = u1*Pp + v1*Pu;
        const float nv = u1*Pq + v1*Pv;
        Pp=np; Pq=nq; Pu=nu; Pv=nv;
    }
    // incoming cp = ex applied to (P applied to 0)
    float cp;
    {
        const float cpP = Pq * frcp(Pv);
        cp = (ep*cpP + eq) * frcp(eu*cpP + ev);
    }

    // ---- Phase C1: cp replay; stash cpv; build (G,H); repurpose va->gv, vf->hv ----
    float cpv[CH];
    float g0 = 0.f, G = 1.f, H = 0.f;
    #pragma unroll
    for (int k = 0; k < CH; ++k) {
        const float am1 = (k == 0)      ? aL : va[k-1];
        const float ap1 = (k == CH - 1) ? aR : va[k+1];
        const float ai = am1 * am1;
        const float bi = 1.0f + va[k]*va[k]*va[k];
        const float ci = ap1 * (ap1 + 2.0f);
        const float rd = frcp(bi - ai*cp);
        cp = ci * rd;
        cpv[k] = cp;
        const float gk = ai * rd;
        const float hk = vf[k] * rd;
        H = hk - gk*H;          // = (f - a*H)*rd
        G = -gk * G;
        if (k == 0) g0 = gk; else va[k-1] = gk;   // gv stash (am1 already read)
        vf[k] = hk;                                // hv stash
    }

    // ---- dp affine wave scan (mine o earlier): H = G*H1 + H; G = G*G1 ----
    #pragma unroll
    for (int off = 1; off < 64; off <<= 1) {
        const float G1 = __shfl_up(G, off);
        const float H1 = __shfl_up(H, off);
        if (lane >= off) { H = G*H1 + H; G = G*G1; }
    }
    if (lane == 63) { wd[wid][0] = G; wd[wid][1] = H; }
    __syncthreads();

    float eG = __shfl_up(G, 1), eH = __shfl_up(H, 1);
    if (lane == 0) { eG = 1.f; eH = 0.f; }
    float Ph = 0.f;
    for (int w = 0; w < wid; ++w) {
        Ph = wd[w][0]*Ph + wd[w][1];   // P = T_w o P (only H-part needed)
    }
    float dp = eG*Ph + eH;   // incoming dp for this chunk

    // ---- Phase C2: dp replay (1 FMA/elem via gv/hv) ----
    float dpv[CH];
    #pragma unroll
    for (int k = 0; k < CH; ++k) {
        const float gk = (k == 0) ? g0 : va[k-1];
        dp = vf[k] - gk*dp;
        dpv[k] = dp;
    }

    // ---- Phase D: backward affine chunk map u_left = A*u_right + B ----
    float A, Bb;
    {   // k = CH-1 from identity
        A = -cpv[CH-1];
        Bb = dpv[CH-1];
    }
    #pragma unroll
    for (int k = CH - 2; k >= 0; --k) {
        Bb = dpv[k] - cpv[k]*Bb;
        A  = -cpv[k]*A;
    }
    // wave-inclusive suffix scan: comp(mine, later)
    #pragma unroll
    for (int off = 1; off < 64; off <<= 1) {
        const float A1 = __shfl_down(A, off);
        const float B1 = __shfl_down(Bb, off);
        if (lane < 64 - off) { Bb = A*B1 + Bb; A = A*A1; }
    }
    if (lane == 0) { wb[wid][0] = A; wb[wid][1] = Bb; }
    __syncthreads();

    float eA = __shfl_down(A, 1), eB = __shfl_down(Bb, 1);
    if (lane == 63) { eA = 1.f; eB = 0.f; }
    float SB = 0.f;
    for (int w = NWAVE - 1; w > wid; --w) {
        SB = wb[w][0]*SB + wb[w][1];
    }
    const float u_in = eA*SB + eB;

    // ---- final back-substitution + float4 stores ----
    float uv[CH];
    float un = u_in;
    #pragma unroll
    for (int k = CH - 1; k >= 0; --k) {
        un = dpv[k] - cpv[k]*un;
        uv[k] = un;
    }
    float4* o4 = reinterpret_cast<float4*>(out + (size_t)row * NN + base);
    #pragma unroll
    for (int k = 0; k < CH / 4; ++k) {
        o4[k] = make_float4(uv[4*k+0], uv[4*k+1], uv[4*k+2], uv[4*k+3]);
    }
}

extern "C" void kernel_launch(void* const* d_in, const int* in_sizes, int n_in,
                              void* d_out, int out_size, void* d_ws, size_t ws_size,
                              hipStream_t stream) {
    const float* alpha = (const float*)d_in[0];
    const float* fvec  = (const float*)d_in[1];
    float* out = (float*)d_out;
    const int nrows = out_size / NN;   // 2048
    thomas_kernel<<<nrows, TB, 0, stream>>>(alpha, fvec, out);
}